// Round 1
// baseline (244.023 us; speedup 1.0000x reference)
//
#include <hip/hip_runtime.h>
#include <stdint.h>

typedef unsigned short u16;
typedef __attribute__((ext_vector_type(8))) __bf16 bf16x8;
typedef __attribute__((ext_vector_type(4))) float f32x4;

__device__ __forceinline__ u16 f2bf(float f) {
    union { float f; uint32_t u; } v; v.f = f;
    uint32_t r = (v.u + 0x7FFFu + ((v.u >> 16) & 1u)) >> 16;
    return (u16)r;
}

__device__ __forceinline__ void lds_fence() {
    __asm__ volatile("s_waitcnt lgkmcnt(0)" ::: "memory");
}

#define BARRIER() __asm__ volatile("s_barrier" ::: "memory")
#define VMW(N)    __asm__ volatile("s_waitcnt vmcnt(" #N ")" ::: "memory")
#define SCHEDB()  __builtin_amdgcn_sched_barrier(0)

// ---------------------------------------------------------------------------
// 256x256 tile, BK=64, 512 threads (8 waves as 2(M) x 4(N), 128x64 per wave).
// 8-phase K-loop (T3+T4): counted vmcnt(4) only at phases 4/8 (never 0 in the
// loop), st-swizzled LDS (T2: (row&8) XOR into colbyte bit 5, realized via
// pre-swizzled global source + swizzled ds_read; LDS dest stays linear for
// global_load_lds), setprio around MFMA clusters (T5), XCD-clustered grid (T1).
//
// LDS (dynamic, 128 KiB): 2 bufs x { A: 2 halves, B: 2 halves } x [2 kblk][128][32] bf16.
//   buf stride 32768 u16, B section +16384, half stride 8192, kblock stride 4096.
// Even K-tiles -> buf0, odd -> buf1 (loop body has fixed buffers).
//
// Stage schedule per iter i (computes kt=2i in p1-4, 2i+1 in p5-8):
//   p1:A1(2i+1) p2:B1(2i+1) p3:B0(2i+2) p4:A0(2i+2)+vmcnt(4)
//   p5:A1(2i+2) p6:B1(2i+2) p7:B0(2i+3) p8:A0(2i+3)+vmcnt(4)
// WAR: each staged half's previous occupant was last ds_read >=1 barrier before.
// RAW: vmcnt(4) at p4/p8 retires everything older than the 2 newest half-tiles,
//      which is exactly the next K-tile's full set. Tail staging wraps mod NT
//      (stale but harmless); epilogue does vmcnt(0)+barrier before LDS reuse.
//
// MODE 0: fused QKV projection, N=3072. Section bn>>10: 0->q(o0,b0),
//         1->k(o1,b1), 2->v(b2) transposed [b,e,s] into o2.
// MODE 2: exp(s*scale) bf16 into o0 + atomic row sums into lsum.
// MODE 3: fp32 out = acc / lsum[row] into o3.
// ---------------------------------------------------------------------------
template<int MODE>
__global__ __launch_bounds__(512, 2) void gemm8(
    const u16* __restrict__ A, const u16* __restrict__ Bt,
    const float* __restrict__ b0, const float* __restrict__ b1, const float* __restrict__ b2,
    u16* __restrict__ o0, u16* __restrict__ o1, u16* __restrict__ o2,
    float* __restrict__ o3, float* __restrict__ lsum,
    int M, int N, int K, long sA, long sB, long sC, float scale)
{
    extern __shared__ __align__(16) u16 smem[];

    const int t = threadIdx.x;
    const int lane = t & 63;
    const int wave = t >> 6;
    const int wm = wave >> 2;   // 0..1
    const int wn = wave & 3;    // 0..3

    // ---- XCD-aware block decode (xcd = id&7 is the HW round-robin) ----
    const int id = blockIdx.x;
    const int xcd = id & 7;
    const int s = id >> 3;
    int bm, bn;
    long bz;
    if (MODE == 0) {            // 384 blocks: 32 bm x 12 bn; XCD k -> bm band [4k,4k+4)
        bm = (xcd * 4 + (s & 3)) * 256;
        bn = (s >> 2) * 256;
        bz = 0;
    } else if (MODE == 2) {     // 256 blocks: 8 bm x 8 bn x 4 z
        bz = xcd >> 1;
        bm = ((xcd & 1) * 4 + (s & 3)) * 256;
        bn = (s >> 2) * 256;
    } else {                    // 128 blocks: 8 bm x 4 bn x 4 z
        bz = xcd >> 1;
        bm = ((xcd & 1) * 4 + (s & 3)) * 256;
        bn = (s >> 2) * 256;
    }

    const u16* Ab = A + bz * sA;
    const u16* Bb = Bt + bz * sB;

    f32x4 acc[8][4];
#pragma unroll
    for (int i = 0; i < 8; ++i)
#pragma unroll
        for (int j = 0; j < 4; ++j)
            acc[i][j] = (f32x4){0.f, 0.f, 0.f, 0.f};

    // ---- staging addressing (per-thread, swizzled global source) ----
    const int trow = t >> 2;                       // 0..127 within half-tile
    const int gcol = ((t & 3) * 8) ^ ((trow & 8) << 1);  // inverse-swz source col
    const u16* aRow = Ab + (long)(bm + trow) * K + gcol;
    const u16* bRow = Bb + (long)(bn + trow) * K + gcol;

    auto stage = [&](int buf, int kt, int h, int isB) {
        const u16* g = (isB ? bRow : aRow) + (long)(h * 128) * K + kt * 64;
        u16* d = smem + t * 8 + buf * 32768 + isB * 16384 + h * 8192;
#pragma unroll
        for (int l = 0; l < 2; ++l)
            __builtin_amdgcn_global_load_lds(
                (const __attribute__((address_space(1))) void*)(g + l * 32),
                (__attribute__((address_space(3))) void*)(d + l * 4096), 16, 0, 0);
    };

    // ---- fragment read addressing (swizzled ds_read) ----
    const int fm = lane & 15;
    const int fcol = ((lane >> 4) * 8) ^ ((fm & 8) << 1);
    const int aB = wm * 8192 + fm * 32 + fcol;                       // + kh*4096 + mh*2048 + mi*512
    const int bB = 16384 + (wn >> 1) * 8192 + (wn & 1) * 2048 + fm * 32 + fcol; // + kh*4096 + nh*1024 + ni*512

    bf16x8 fa[4][2], fb0[2][2], fb1[2][2];

#define RD_A(BUF, MH) do { \
    _Pragma("unroll") for (int mi = 0; mi < 4; ++mi) \
    _Pragma("unroll") for (int kh = 0; kh < 2; ++kh) \
        fa[mi][kh] = *(const bf16x8*)&smem[(BUF)*32768 + aB + kh*4096 + (MH)*2048 + mi*512]; \
} while (0)

#define RD_B(BUF, NH, DST) do { \
    _Pragma("unroll") for (int ni = 0; ni < 2; ++ni) \
    _Pragma("unroll") for (int kh = 0; kh < 2; ++kh) \
        DST[ni][kh] = *(const bf16x8*)&smem[(BUF)*32768 + bB + kh*4096 + (NH)*1024 + ni*512]; \
} while (0)

#define QUAD(MH, NH, FB) do { \
    __builtin_amdgcn_s_setprio(1); \
    _Pragma("unroll") for (int mi = 0; mi < 4; ++mi) \
    _Pragma("unroll") for (int ni = 0; ni < 2; ++ni) \
    _Pragma("unroll") for (int kh = 0; kh < 2; ++kh) \
        acc[(MH)*4+mi][(NH)*2+ni] = __builtin_amdgcn_mfma_f32_16x16x32_bf16( \
            fa[mi][kh], FB[ni][kh], acc[(MH)*4+mi][(NH)*2+ni], 0, 0, 0); \
    __builtin_amdgcn_s_setprio(0); \
} while (0)

    const int NT = K >> 6;      // K-tiles (even: 16 or 32)
    const int NI = NT >> 1;

    // ---- prologue: K-tile 0 (4 half-tiles) + B0(1), A0(1); keep last 4 loads in flight ----
    stage(0, 0, 0, 0); stage(0, 0, 1, 0); stage(0, 0, 0, 1); stage(0, 0, 1, 1);
    stage(1, 1, 0, 1); stage(1, 1, 0, 0);
    VMW(4);
    BARRIER();

    for (int i = 0; i < NI; ++i) {
        const int knext = 2 * i + 1;
        int ktc = 2 * i + 2; if (ktc >= NT) ktc -= NT;   // wraps only on last iter (stale-safe)
        const int ktd = ktc + 1;

        // P1
        RD_A(0, 0); RD_B(0, 0, fb0);
        stage(1, knext, 1, 0);
        BARRIER(); SCHEDB();
        QUAD(0, 0, fb0);
        BARRIER();
        // P2
        RD_B(0, 1, fb1);
        stage(1, knext, 1, 1);
        BARRIER(); SCHEDB();
        QUAD(0, 1, fb1);
        BARRIER();
        // P3
        RD_A(0, 1);
        stage(0, ktc, 0, 1);
        BARRIER(); SCHEDB();
        QUAD(1, 1, fb1);
        BARRIER();
        // P4
        stage(0, ktc, 0, 0);
        BARRIER(); SCHEDB();
        QUAD(1, 0, fb0);
        VMW(4);
        BARRIER();
        // P5
        RD_A(1, 0); RD_B(1, 0, fb0);
        stage(0, ktc, 1, 0);
        BARRIER(); SCHEDB();
        QUAD(0, 0, fb0);
        BARRIER();
        // P6
        RD_B(1, 1, fb1);
        stage(0, ktc, 1, 1);
        BARRIER(); SCHEDB();
        QUAD(0, 1, fb1);
        BARRIER();
        // P7
        RD_A(1, 1);
        stage(1, ktd, 0, 1);
        BARRIER(); SCHEDB();
        QUAD(1, 1, fb1);
        BARRIER();
        // P8
        stage(1, ktd, 0, 0);
        BARRIER(); SCHEDB();
        QUAD(1, 0, fb0);
        VMW(4);
        BARRIER();
    }

    // ---- drain stale in-flight stagers before LDS reuse ----
    VMW(0);
    BARRIER();

    // C/D layout: col = lane&15, row = (lane>>4)*4 + reg
    const int cm = (lane >> 4) * 4;
    const int cn = lane & 15;
    u16* Ew = smem + wave * 8192;      // 16 KiB per-wave window
    const int gmb = bm + wm * 128;
    const int cnb = bn + wn * 64;

    if (MODE == 3) {
        // ---- fp32 out (PV), /lsum[row]: 4 passes of 32 rows, stride 68 fp32 ----
        float* Fw = (float*)Ew;
#pragma unroll
        for (int p = 0; p < 4; ++p) {
            if (p) lds_fence();
#pragma unroll
            for (int m2 = 0; m2 < 2; ++m2) {
                const int mi = p * 2 + m2;
#pragma unroll
                for (int ni = 0; ni < 4; ++ni)
#pragma unroll
                    for (int r = 0; r < 4; ++r)
                        Fw[(m2 * 16 + cm + r) * 68 + ni * 16 + cn] = acc[mi][ni][r];
            }
#pragma unroll
            for (int it = 0; it < 8; ++it) {
                const int row = it * 4 + (lane >> 4);
                const int c4 = cn * 4;
                f32x4 w = *(const f32x4*)&Fw[row * 68 + c4];
                const int gm = gmb + p * 32 + row;
                const float inv = __builtin_amdgcn_rcpf(lsum[bz * 2048 + gm]);
                w[0] *= inv; w[1] *= inv; w[2] *= inv; w[3] *= inv;
                *(f32x4*)&o3[bz * sC + (long)gm * N + cnb + c4] = w;
            }
        }
    } else if (MODE == 0 && (bn >> 10) == 2) {
        // ---- v projection: transposed [b,e,s]; 2 s-passes of 64 ----
        const int ebase = (bn & 1023) + wn * 64;
        float bb[4];
#pragma unroll
        for (int ni = 0; ni < 4; ++ni) bb[ni] = b2[ebase + ni * 16 + cn];
        const long bgi = gmb >> 11;
        const int sbase = gmb & 2047;
#pragma unroll
        for (int p = 0; p < 2; ++p) {
            if (p) lds_fence();
#pragma unroll
            for (int m4 = 0; m4 < 4; ++m4) {
                const int mi = p * 4 + m4;
#pragma unroll
                for (int ni = 0; ni < 4; ++ni) {
                    ushort4 pk;
                    pk.x = f2bf(acc[mi][ni][0] + bb[ni]);
                    pk.y = f2bf(acc[mi][ni][1] + bb[ni]);
                    pk.z = f2bf(acc[mi][ni][2] + bb[ni]);
                    pk.w = f2bf(acc[mi][ni][3] + bb[ni]);
                    *(ushort4*)&Ew[(ni * 16 + cn) * 72 + m4 * 16 + cm] = pk; // [e][s]
                }
            }
#pragma unroll
            for (int it = 0; it < 8; ++it) {
                const int e = it * 8 + (lane >> 3);
                const int s8 = (lane & 7) * 8;
                const uint4 w = *(const uint4*)&Ew[e * 72 + s8];
                *(uint4*)&o2[(((bgi << 10) + ebase + e) << 11) + sbase + p * 64 + s8] = w;
            }
        }
    } else if (MODE == 0) {
        // ---- q/k projection, row-major bf16; 2 row-passes of 64 ----
        const int sec = bn >> 10;
        u16* C = sec ? o1 : o0;
        const float* bias = sec ? b1 : b0;
        const int ncol0 = (bn & 1023) + wn * 64;
        float bb[4];
#pragma unroll
        for (int ni = 0; ni < 4; ++ni) bb[ni] = bias[ncol0 + ni * 16 + cn];
#pragma unroll
        for (int p = 0; p < 2; ++p) {
            if (p) lds_fence();
#pragma unroll
            for (int m4 = 0; m4 < 4; ++m4) {
                const int mi = p * 4 + m4;
#pragma unroll
                for (int ni = 0; ni < 4; ++ni)
#pragma unroll
                    for (int r = 0; r < 4; ++r)
                        Ew[(m4 * 16 + cm + r) * 72 + ni * 16 + cn] = f2bf(acc[mi][ni][r] + bb[ni]);
            }
#pragma unroll
            for (int it = 0; it < 8; ++it) {
                const int row = it * 8 + (lane >> 3);
                const int c8 = (lane & 7) * 8;
                const uint4 w = *(const uint4*)&Ew[row * 72 + c8];
                *(uint4*)&C[(long)(gmb + p * 64 + row) * 1024 + ncol0 + c8] = w;
            }
        }
    } else {
        // ---- MODE 2: exp(s*scale), row-sum atomics, bf16 retile ----
#pragma unroll
        for (int mi = 0; mi < 8; ++mi)
#pragma unroll
            for (int ni = 0; ni < 4; ++ni)
#pragma unroll
                for (int r = 0; r < 4; ++r)
                    acc[mi][ni][r] = __expf(acc[mi][ni][r] * scale);
#pragma unroll
        for (int mi = 0; mi < 8; ++mi) {
#pragma unroll
            for (int r = 0; r < 4; ++r) {
                float sm = acc[mi][0][r] + acc[mi][1][r] + acc[mi][2][r] + acc[mi][3][r];
                sm += __shfl_xor(sm, 1);
                sm += __shfl_xor(sm, 2);
                sm += __shfl_xor(sm, 4);
                sm += __shfl_xor(sm, 8);
                if (cn == 0)
                    atomicAdd(&lsum[bz * 2048 + gmb + mi * 16 + cm + r], sm);
            }
        }
#pragma unroll
        for (int p = 0; p < 2; ++p) {
            if (p) lds_fence();
#pragma unroll
            for (int m4 = 0; m4 < 4; ++m4) {
                const int mi = p * 4 + m4;
#pragma unroll
                for (int ni = 0; ni < 4; ++ni)
#pragma unroll
                    for (int r = 0; r < 4; ++r)
                        Ew[(m4 * 16 + cm + r) * 72 + ni * 16 + cn] = f2bf(acc[mi][ni][r]);
            }
#pragma unroll
            for (int it = 0; it < 8; ++it) {
                const int row = it * 8 + (lane >> 3);
                const int c8 = (lane & 7) * 8;
                const uint4 w = *(const uint4*)&Ew[row * 72 + c8];
                *(uint4*)&o0[bz * sC + (long)(gmb + p * 64 + row) * N + cnb + c8] = w;
            }
        }
    }
}

#undef RD_A
#undef RD_B
#undef QUAD

// fp32 -> bf16 converts + lsum zeroing.
__global__ __launch_bounds__(256) void cvt_all(
    const float* __restrict__ x, const float* __restrict__ wq,
    const float* __restrict__ wk, const float* __restrict__ wv,
    u16* __restrict__ xb, u16* __restrict__ wb, float* __restrict__ lsum)
{
    const int b = blockIdx.x;
    if (b >= 11264) {
        const long i = (long)(b - 11264) * 1024 + threadIdx.x * 4;
        *(f32x4*)(lsum + i) = (f32x4){0.f, 0.f, 0.f, 0.f};
        return;
    }
    const float* src; u16* dst; long base;
    if (b < 8192)       { src = x;  dst = xb;             base = (long)b * 1024; }
    else if (b < 9216)  { src = wq; dst = wb;             base = (long)(b - 8192) * 1024; }
    else if (b < 10240) { src = wk; dst = wb + (1 << 20); base = (long)(b - 9216) * 1024; }
    else                { src = wv; dst = wb + (2 << 20); base = (long)(b - 10240) * 1024; }
    const long i = base + threadIdx.x * 4;
    const f32x4 f = *(const f32x4*)(src + i);
    ushort4 o;
    o.x = f2bf(f[0]); o.y = f2bf(f[1]); o.z = f2bf(f[2]); o.w = f2bf(f[3]);
    *(ushort4*)(dst + i) = o;
}

extern "C" void kernel_launch(void* const* d_in, const int* in_sizes, int n_in,
                              void* d_out, int out_size, void* d_ws, size_t ws_size,
                              hipStream_t stream) {
    const float* x  = (const float*)d_in[0];
    const float* Wq = (const float*)d_in[1];
    const float* bq = (const float*)d_in[2];
    const float* Wk = (const float*)d_in[3];
    const float* bk = (const float*)d_in[4];
    const float* Wv = (const float*)d_in[5];
    const float* bv = (const float*)d_in[6];
    float* out = (float*)d_out;

    const int B = 4, S = 2048, D = 1024, E = 1024;
    const int M = B * S; // 8192
    const size_t LDS = 131072;

    u16* xb  = (u16*)d_ws;                       // [M,D]
    u16* wb  = xb  + (size_t)M * D;              // [3E,D]
    u16* qb  = wb  + (size_t)3 * E * D;          // [M,E]
    u16* kb  = qb  + (size_t)M * E;              // [M,E]
    u16* vbT = kb  + (size_t)M * E;              // [B,E,S]
    u16* sb  = vbT + (size_t)M * E;              // [B,S,S] exp-scores
    float* lsum = (float*)(sb + (size_t)M * S);  // [M]

    static bool attr_done = false;
    if (!attr_done) {
        (void)hipFuncSetAttribute((const void*)gemm8<0>, hipFuncAttributeMaxDynamicSharedMemorySize, (int)LDS);
        (void)hipFuncSetAttribute((const void*)gemm8<2>, hipFuncAttributeMaxDynamicSharedMemorySize, (int)LDS);
        (void)hipFuncSetAttribute((const void*)gemm8<3>, hipFuncAttributeMaxDynamicSharedMemorySize, (int)LDS);
        attr_done = true;
    }

    cvt_all<<<11272, 256, 0, stream>>>(x, Wq, Wk, Wv, xb, wb, lsum);

    dim3 blk(512);
    gemm8<0><<<384, blk, LDS, stream>>>(
        xb, wb, bq, bk, bv, qb, kb, vbT, nullptr, nullptr, M, 3 * E, D, 0, 0, 0, 1.f);
    gemm8<2><<<256, blk, LDS, stream>>>(
        qb, kb, nullptr, nullptr, nullptr, sb, nullptr, nullptr, nullptr, lsum,
        S, S, E, (long)S * E, (long)S * E, (long)S * S, 0.03125f);
    gemm8<3><<<128, blk, LDS, stream>>>(
        sb, vbT, nullptr, nullptr, nullptr, nullptr, nullptr, nullptr, out, lsum,
        S, E, S, (long)S * S, (long)E * S, (long)S * E, 1.f);
}

// Round 2
// 231.191 us; speedup vs baseline: 1.0555x; 1.0555x over previous
//
#include <hip/hip_runtime.h>
#include <stdint.h>

typedef unsigned short u16;
typedef __attribute__((ext_vector_type(8))) __bf16 bf16x8;
typedef __attribute__((ext_vector_type(4))) float f32x4;

__device__ __forceinline__ u16 f2bf(float f) {
    union { float f; uint32_t u; } v; v.f = f;
    uint32_t r = (v.u + 0x7FFFu + ((v.u >> 16) & 1u)) >> 16;
    return (u16)r;
}

__device__ __forceinline__ void lds_fence() {
    __asm__ volatile("s_waitcnt lgkmcnt(0)" ::: "memory");
}

#define BARRIER() __builtin_amdgcn_s_barrier()
#define VMW(N)    __asm__ volatile("s_waitcnt vmcnt(" #N ")" ::: "memory")

// ---------------------------------------------------------------------------
// 256-wide-M tile, BK=64, 512 threads (8 waves 2M x 4N).
// Modes 0/2: BN=256 (per-wave 128x64, acc[8][4]). Mode 3: BN=128 (per-wave
// 128x32, acc[8][2]) so PV gets 256 blocks (was 128 = half the CUs idle).
// 8-phase K-loop, counted vmcnt (T4): every forced-retired load has been in
// flight >=3 phases. No sched_barrier (m141: pinning defeats the scheduler).
// T2 LDS swizzle via pre-swizzled global source + swizzled ds_read (LDS dest
// linear for global_load_lds). T5 setprio around MFMA clusters. T1 XCD grid.
//
// LDS: 2 bufs x { A: 2 halves, B: 2 (1 for MODE3) } x [2 kblk][128][32] bf16.
// buf stride 32768 u16, B section +16384, half stride 8192, kblock 4096.
//
// Stage schedule per iter (computes t=2i @P1-4 buf0, t+1 @P5-8 buf1):
//   P1:A1(t+1) P2:B1(t+1)* P3:B0(t+2) P4:A0(t+2) P5:A1(t+2) P6:B1(t+2)*
//   P7:B0(t+3) P8:A0(t+3)          (* skipped for MODE3)
// Waits modes 0/2: VMW(6) at P1/P4/P5/P8 ends. MODE3: VMW(4) at P4/P8.
// FIFO ledger (verified): each wait retires exactly the half-tiles read next
// phase, all staged >=3 phases prior. WAR: every slot's last ds_read is >=1
// barrier before its restage. Tail wraps mod NT (stale-safe); epilogue
// VMW(0)+barrier before LDS reuse.
//
// MODE 0: fused QKV, N=3072, 384 blocks. bn>>10: 0->q(o0,b0), 1->k(o1,b1),
//         2->v(b2) transposed [b,e,s] into o2.
// MODE 2: exp(s*scale) bf16 into o0 + atomic row sums into lsum. 256 blocks.
// MODE 3: fp32 out = acc / lsum[row] into o3. 256 blocks (BN=128).
// ---------------------------------------------------------------------------
template<int MODE>
__global__ __launch_bounds__(512, 2) void gemm8(
    const u16* __restrict__ A, const u16* __restrict__ Bt,
    const float* __restrict__ b0, const float* __restrict__ b1, const float* __restrict__ b2,
    u16* __restrict__ o0, u16* __restrict__ o1, u16* __restrict__ o2,
    float* __restrict__ o3, float* __restrict__ lsum,
    int M, int N, int K, long sA, long sB, long sC, float scale)
{
    extern __shared__ __align__(16) u16 smem[];
    constexpr int NIR = (MODE == 3) ? 1 : 2;      // ni frags per NH group
    constexpr int NJ  = (MODE == 3) ? 2 : 4;      // acc N columns
    constexpr int NHS = (MODE == 3) ? 512 : 1024; // NH stride in B LDS (u16)

    const int t = threadIdx.x;
    const int lane = t & 63;
    const int wave = t >> 6;
    const int wm = wave >> 2;   // 0..1
    const int wn = wave & 3;    // 0..3

    const int id = blockIdx.x;
    const int xcd = id & 7;
    const int s = id >> 3;
    int bm, bn;
    long bz;
    if (MODE == 0) {            // 384 blocks: 32 bm x 12 bn
        bm = (xcd * 4 + (s & 3)) * 256;
        bn = (s >> 2) * 256;
        bz = 0;
    } else if (MODE == 2) {     // 256 blocks: 8 bm x 8 bn x 4 z
        bz = xcd >> 1;
        bm = ((xcd & 1) * 4 + (s & 3)) * 256;
        bn = (s >> 2) * 256;
    } else {                    // 256 blocks: 8 bm x 8 bn(128) x 4 z
        bz = xcd >> 1;
        bm = ((xcd & 1) * 4 + (s & 3)) * 256;
        bn = (s >> 2) * 128;
    }

    const u16* Ab = A + bz * sA;
    const u16* Bb = Bt + bz * sB;

    f32x4 acc[8][NJ];
#pragma unroll
    for (int i = 0; i < 8; ++i)
#pragma unroll
        for (int j = 0; j < NJ; ++j)
            acc[i][j] = (f32x4){0.f, 0.f, 0.f, 0.f};

    // ---- staging addressing (per-thread, inverse-swizzled global source) ----
    const int trow = t >> 2;                             // 0..127
    const int gcol = ((t & 3) * 8) ^ ((trow & 8) << 1);
    const u16* aRow = Ab + (long)(bm + trow) * K + gcol;
    const u16* bRow = Bb + (long)(bn + trow) * K + gcol;

    auto stage = [&](int buf, int kt, int h, int isB) {
        const u16* g = (isB ? bRow : aRow) + (long)(h * 128) * K + kt * 64;
        u16* d = smem + t * 8 + buf * 32768 + isB * 16384 + h * 8192;
#pragma unroll
        for (int l = 0; l < 2; ++l)
            __builtin_amdgcn_global_load_lds(
                (const __attribute__((address_space(1))) void*)(g + l * 32),
                (__attribute__((address_space(3))) void*)(d + l * 4096), 16, 0, 0);
    };

    // ---- fragment read addressing (swizzled ds_read) ----
    const int fm = lane & 15;
    const int fcol = ((lane >> 4) * 8) ^ ((fm & 8) << 1);
    const int aB = wm * 8192 + fm * 32 + fcol;
    const int bB = (MODE == 3)
        ? 16384 + wn * 1024 + fm * 32 + fcol
        : 16384 + (wn >> 1) * 8192 + (wn & 1) * 2048 + fm * 32 + fcol;

    bf16x8 fa[4][2], fb0[NIR][2], fb1[NIR][2];

#define RD_A(BUF, MH) do { \
    _Pragma("unroll") for (int mi = 0; mi < 4; ++mi) \
    _Pragma("unroll") for (int kh = 0; kh < 2; ++kh) \
        fa[mi][kh] = *(const bf16x8*)&smem[(BUF)*32768 + aB + kh*4096 + (MH)*2048 + mi*512]; \
} while (0)

#define RD_B(BUF, NH, DST) do { \
    _Pragma("unroll") for (int ni = 0; ni < NIR; ++ni) \
    _Pragma("unroll") for (int kh = 0; kh < 2; ++kh) \
        DST[ni][kh] = *(const bf16x8*)&smem[(BUF)*32768 + bB + kh*4096 + (NH)*NHS + ni*512]; \
} while (0)

#define QUAD(MH, NH, FB) do { \
    __builtin_amdgcn_s_setprio(1); \
    _Pragma("unroll") for (int mi = 0; mi < 4; ++mi) \
    _Pragma("unroll") for (int ni = 0; ni < NIR; ++ni) \
    _Pragma("unroll") for (int kh = 0; kh < 2; ++kh) \
        acc[(MH)*4+mi][(NH)*NIR+ni] = __builtin_amdgcn_mfma_f32_16x16x32_bf16( \
            fa[mi][kh], FB[ni][kh], acc[(MH)*4+mi][(NH)*NIR+ni], 0, 0, 0); \
    __builtin_amdgcn_s_setprio(0); \
} while (0)

    const int NT = K >> 6;
    const int NI = NT >> 1;

    // ---- prologue ----
    stage(0, 0, 0, 0); stage(0, 0, 1, 0); stage(0, 0, 0, 1);
    if (MODE != 3) stage(0, 0, 1, 1);
    stage(1, 1, 0, 1); stage(1, 1, 0, 0);
    if (MODE == 3) { VMW(4); } else { VMW(6); }
    BARRIER();

    for (int i = 0; i < NI; ++i) {
        const int knext = 2 * i + 1;
        int ktc = 2 * i + 2; if (ktc >= NT) ktc -= NT;
        const int ktd = ktc + 1;

        // P1
        RD_A(0, 0); RD_B(0, 0, fb0);
        stage(1, knext, 1, 0);
        BARRIER();
        QUAD(0, 0, fb0);
        if (MODE != 3) VMW(6);
        BARRIER();
        // P2
        RD_B(0, 1, fb1);
        if (MODE != 3) stage(1, knext, 1, 1);
        BARRIER();
        QUAD(0, 1, fb1);
        BARRIER();
        // P3
        RD_A(0, 1);
        stage(0, ktc, 0, 1);
        BARRIER();
        QUAD(1, 1, fb1);
        BARRIER();
        // P4
        stage(0, ktc, 0, 0);
        BARRIER();
        QUAD(1, 0, fb0);
        if (MODE == 3) { VMW(4); } else { VMW(6); }
        BARRIER();
        // P5
        RD_A(1, 0); RD_B(1, 0, fb0);
        stage(0, ktc, 1, 0);
        BARRIER();
        QUAD(0, 0, fb0);
        if (MODE != 3) VMW(6);
        BARRIER();
        // P6
        RD_B(1, 1, fb1);
        if (MODE != 3) stage(0, ktc, 1, 1);
        BARRIER();
        QUAD(0, 1, fb1);
        BARRIER();
        // P7
        RD_A(1, 1);
        stage(1, ktd, 0, 1);
        BARRIER();
        QUAD(1, 1, fb1);
        BARRIER();
        // P8
        stage(1, ktd, 0, 0);
        BARRIER();
        QUAD(1, 0, fb0);
        if (MODE == 3) { VMW(4); } else { VMW(6); }
        BARRIER();
    }

    // ---- drain stale in-flight stagers before LDS reuse ----
    VMW(0);
    BARRIER();

    // C/D layout: col = lane&15, row = (lane>>4)*4 + reg
    const int cm = (lane >> 4) * 4;
    const int cn = lane & 15;
    u16* Ew = smem + wave * 8192;      // 16 KiB per-wave window
    const int gmb = bm + wm * 128;

    if constexpr (MODE == 3) {
        // ---- fp32 out (PV), /lsum[row]: 4 passes of 32 rows x 32 cols ----
        float* Fw = (float*)Ew;
        const int cnb3 = bn + wn * 32;
#pragma unroll
        for (int p = 0; p < 4; ++p) {
            if (p) lds_fence();
#pragma unroll
            for (int m2 = 0; m2 < 2; ++m2) {
                const int mi = p * 2 + m2;
#pragma unroll
                for (int ni = 0; ni < 2; ++ni)
#pragma unroll
                    for (int r = 0; r < 4; ++r)
                        Fw[(m2 * 16 + cm + r) * 36 + ni * 16 + cn] = acc[mi][ni][r];
            }
#pragma unroll
            for (int it = 0; it < 4; ++it) {
                const int row = it * 8 + (lane >> 3);
                const int c4 = (lane & 7) * 4;
                f32x4 w = *(const f32x4*)&Fw[row * 36 + c4];
                const int gm = gmb + p * 32 + row;
                const float inv = __builtin_amdgcn_rcpf(lsum[bz * 2048 + gm]);
                w[0] *= inv; w[1] *= inv; w[2] *= inv; w[3] *= inv;
                *(f32x4*)&o3[bz * sC + (long)gm * N + cnb3 + c4] = w;
            }
        }
    } else if (MODE == 0 && (bn >> 10) == 2) {
        // ---- v projection: transposed [b,e,s]; 2 s-passes of 64 ----
        const int ebase = (bn & 1023) + wn * 64;
        float bb[4];
#pragma unroll
        for (int ni = 0; ni < 4; ++ni) bb[ni] = b2[ebase + ni * 16 + cn];
        const long bgi = gmb >> 11;
        const int sbase = gmb & 2047;
#pragma unroll
        for (int p = 0; p < 2; ++p) {
            if (p) lds_fence();
#pragma unroll
            for (int m4 = 0; m4 < 4; ++m4) {
                const int mi = p * 4 + m4;
#pragma unroll
                for (int ni = 0; ni < 4; ++ni) {
                    ushort4 pk;
                    pk.x = f2bf(acc[mi][ni][0] + bb[ni]);
                    pk.y = f2bf(acc[mi][ni][1] + bb[ni]);
                    pk.z = f2bf(acc[mi][ni][2] + bb[ni]);
                    pk.w = f2bf(acc[mi][ni][3] + bb[ni]);
                    *(ushort4*)&Ew[(ni * 16 + cn) * 72 + m4 * 16 + cm] = pk; // [e][s]
                }
            }
#pragma unroll
            for (int it = 0; it < 8; ++it) {
                const int e = it * 8 + (lane >> 3);
                const int s8 = (lane & 7) * 8;
                const uint4 w = *(const uint4*)&Ew[e * 72 + s8];
                *(uint4*)&o2[(((bgi << 10) + ebase + e) << 11) + sbase + p * 64 + s8] = w;
            }
        }
    } else if (MODE == 0) {
        // ---- q/k projection, row-major bf16; 2 row-passes of 64 ----
        const int sec = bn >> 10;
        u16* C = sec ? o1 : o0;
        const float* bias = sec ? b1 : b0;
        const int ncol0 = (bn & 1023) + wn * 64;
        float bb[4];
#pragma unroll
        for (int ni = 0; ni < 4; ++ni) bb[ni] = bias[ncol0 + ni * 16 + cn];
#pragma unroll
        for (int p = 0; p < 2; ++p) {
            if (p) lds_fence();
#pragma unroll
            for (int m4 = 0; m4 < 4; ++m4) {
                const int mi = p * 4 + m4;
#pragma unroll
                for (int ni = 0; ni < 4; ++ni)
#pragma unroll
                    for (int r = 0; r < 4; ++r)
                        Ew[(m4 * 16 + cm + r) * 72 + ni * 16 + cn] = f2bf(acc[mi][ni][r] + bb[ni]);
            }
#pragma unroll
            for (int it = 0; it < 8; ++it) {
                const int row = it * 8 + (lane >> 3);
                const int c8 = (lane & 7) * 8;
                const uint4 w = *(const uint4*)&Ew[row * 72 + c8];
                *(uint4*)&C[(long)(gmb + p * 64 + row) * 1024 + ncol0 + c8] = w;
            }
        }
    } else {
        // ---- MODE 2: exp(s*scale), row-sum atomics, bf16 retile ----
        const int cnb = bn + wn * 64;
#pragma unroll
        for (int mi = 0; mi < 8; ++mi)
#pragma unroll
            for (int ni = 0; ni < 4; ++ni)
#pragma unroll
                for (int r = 0; r < 4; ++r)
                    acc[mi][ni][r] = __expf(acc[mi][ni][r] * scale);
#pragma unroll
        for (int mi = 0; mi < 8; ++mi) {
#pragma unroll
            for (int r = 0; r < 4; ++r) {
                float sm = acc[mi][0][r] + acc[mi][1][r] + acc[mi][2][r] + acc[mi][3][r];
                sm += __shfl_xor(sm, 1);
                sm += __shfl_xor(sm, 2);
                sm += __shfl_xor(sm, 4);
                sm += __shfl_xor(sm, 8);
                if (cn == 0)
                    atomicAdd(&lsum[bz * 2048 + gmb + mi * 16 + cm + r], sm);
            }
        }
#pragma unroll
        for (int p = 0; p < 2; ++p) {
            if (p) lds_fence();
#pragma unroll
            for (int m4 = 0; m4 < 4; ++m4) {
                const int mi = p * 4 + m4;
#pragma unroll
                for (int ni = 0; ni < 4; ++ni)
#pragma unroll
                    for (int r = 0; r < 4; ++r)
                        Ew[(m4 * 16 + cm + r) * 72 + ni * 16 + cn] = f2bf(acc[mi][ni][r]);
            }
#pragma unroll
            for (int it = 0; it < 8; ++it) {
                const int row = it * 8 + (lane >> 3);
                const int c8 = (lane & 7) * 8;
                const uint4 w = *(const uint4*)&Ew[row * 72 + c8];
                *(uint4*)&o0[bz * sC + (long)(gmb + p * 64 + row) * N + cnb + c8] = w;
            }
        }
    }
}

#undef RD_A
#undef RD_B
#undef QUAD

// fp32 -> bf16 converts + lsum zeroing.
__global__ __launch_bounds__(256) void cvt_all(
    const float* __restrict__ x, const float* __restrict__ wq,
    const float* __restrict__ wk, const float* __restrict__ wv,
    u16* __restrict__ xb, u16* __restrict__ wb, float* __restrict__ lsum)
{
    const int b = blockIdx.x;
    if (b >= 11264) {
        const long i = (long)(b - 11264) * 1024 + threadIdx.x * 4;
        *(f32x4*)(lsum + i) = (f32x4){0.f, 0.f, 0.f, 0.f};
        return;
    }
    const float* src; u16* dst; long base;
    if (b < 8192)       { src = x;  dst = xb;             base = (long)b * 1024; }
    else if (b < 9216)  { src = wq; dst = wb;             base = (long)(b - 8192) * 1024; }
    else if (b < 10240) { src = wk; dst = wb + (1 << 20); base = (long)(b - 9216) * 1024; }
    else                { src = wv; dst = wb + (2 << 20); base = (long)(b - 10240) * 1024; }
    const long i = base + threadIdx.x * 4;
    const f32x4 f = *(const f32x4*)(src + i);
    ushort4 o;
    o.x = f2bf(f[0]); o.y = f2bf(f[1]); o.z = f2bf(f[2]); o.w = f2bf(f[3]);
    *(ushort4*)(dst + i) = o;
}

extern "C" void kernel_launch(void* const* d_in, const int* in_sizes, int n_in,
                              void* d_out, int out_size, void* d_ws, size_t ws_size,
                              hipStream_t stream) {
    const float* x  = (const float*)d_in[0];
    const float* Wq = (const float*)d_in[1];
    const float* bq = (const float*)d_in[2];
    const float* Wk = (const float*)d_in[3];
    const float* bk = (const float*)d_in[4];
    const float* Wv = (const float*)d_in[5];
    const float* bv = (const float*)d_in[6];
    float* out = (float*)d_out;

    const int B = 4, S = 2048, D = 1024, E = 1024;
    const int M = B * S; // 8192
    const size_t LDS = 131072;

    u16* xb  = (u16*)d_ws;                       // [M,D]
    u16* wb  = xb  + (size_t)M * D;              // [3E,D]
    u16* qb  = wb  + (size_t)3 * E * D;          // [M,E]
    u16* kb  = qb  + (size_t)M * E;              // [M,E]
    u16* vbT = kb  + (size_t)M * E;              // [B,E,S]
    u16* sb  = vbT + (size_t)M * E;              // [B,S,S] exp-scores
    float* lsum = (float*)(sb + (size_t)M * S);  // [M]

    static bool attr_done = false;
    if (!attr_done) {
        (void)hipFuncSetAttribute((const void*)gemm8<0>, hipFuncAttributeMaxDynamicSharedMemorySize, (int)LDS);
        (void)hipFuncSetAttribute((const void*)gemm8<2>, hipFuncAttributeMaxDynamicSharedMemorySize, (int)LDS);
        (void)hipFuncSetAttribute((const void*)gemm8<3>, hipFuncAttributeMaxDynamicSharedMemorySize, (int)LDS);
        attr_done = true;
    }

    cvt_all<<<11272, 256, 0, stream>>>(x, Wq, Wk, Wv, xb, wb, lsum);

    dim3 blk(512);
    gemm8<0><<<384, blk, LDS, stream>>>(
        xb, wb, bq, bk, bv, qb, kb, vbT, nullptr, nullptr, M, 3 * E, D, 0, 0, 0, 1.f);
    gemm8<2><<<256, blk, LDS, stream>>>(
        qb, kb, nullptr, nullptr, nullptr, sb, nullptr, nullptr, nullptr, lsum,
        S, S, E, (long)S * E, (long)S * E, (long)S * S, 0.03125f);
    gemm8<3><<<256, blk, LDS, stream>>>(
        sb, vbT, nullptr, nullptr, nullptr, nullptr, nullptr, nullptr, out, lsum,
        S, E, S, (long)S * S, (long)E * S, (long)S * E, 1.f);
}

// Round 3
// 227.867 us; speedup vs baseline: 1.0709x; 1.0146x over previous
//
#include <hip/hip_runtime.h>
#include <stdint.h>

typedef unsigned short u16;
typedef __attribute__((ext_vector_type(8))) __bf16 bf16x8;
typedef __attribute__((ext_vector_type(4))) float f32x4;

__device__ __forceinline__ u16 f2bf(float f) {
    union { float f; uint32_t u; } v; v.f = f;
    uint32_t r = (v.u + 0x7FFFu + ((v.u >> 16) & 1u)) >> 16;
    return (u16)r;
}

__device__ __forceinline__ void lds_fence() {
    __asm__ volatile("s_waitcnt lgkmcnt(0)" ::: "memory");
}

#define BAR()  __asm__ volatile("s_barrier" ::: "memory")
#define VMW(N) __asm__ volatile("s_waitcnt vmcnt(" #N ")" ::: "memory")

// ---------------------------------------------------------------------------
// 256-wide-M tile, BK=64, 512 threads (8 waves 2M x 4N). Modes 0/2: BN=256
// (acc[8][4]); Mode 3: BN=128 (acc[8][2], 256 blocks).
//
// ROUND-3 STRUCTURE: one barrier per phase + one-phase-ahead ds_reads.
// Phase p = { MFMA(p) on frags read in p-1 | [odd p: VMW] | ds_read frags for
// p+1 | stage 2 chunks | s_barrier }. The p+1 reads drain in the LDS pipe
// while other waves finish MFMA(p) -> DS (4.6kcy/iter/CU) hides under MFMA
// (5.0kcy/iter/CU) instead of serializing (was ~9kcy -> 50% util).
// kh-major compute split: P1:mh0*kh0 P2:mh1*kh0 P3:mh0*kh1 P4:mh1*kh1 (buf0),
// P5-8 same on buf1. Read issue per phase: 4/8/4/8 balanced; B frags reused
// across 2 phases.
//
// LDS: 2 bufs x { A[2h][2k][128][32], B same (mode3: B 1h) } bf16, 128 KiB.
// chunk = 1 global_load_lds instr = (isB,h,k) 128x32 = 8KB.
// Stage schedule (t=2i): P1:B1k1<-t+1 P2:A1k1<-t+1 P3:B0k0<-t+2 P4:A0k0
//   P5:B0k1 P6:A0k1 P7:B1k0<-t+3 P8:A1k0<-t+3.  (B chunks: 1 for mode3.)
// VMW(6) (mode3: VMW(4)) at END of odd phases, BEFORE the barrier (cross-wave
// arrival guarantee requires every wave's VMW to precede every read of the
// staged data). FIFO ledger verified for steady state AND iter 0: each wait
// retires exactly the chunks read after the next barrier, staged 4-5 phases
// earlier. Stage-vs-last-read-issue separation >= 3 barriers (WAR safe).
// Tail wraps mod NT (stale-safe); epilogue VMW(0)+barrier before LDS reuse.
//
// T1 XCD grid swizzle; T2 swizzle via pre-swizzled global source + swizzled
// ds_read (LDS dest linear); T5 setprio around MFMA clusters.
//
// MODE 0: fused QKV, N=3072, 384 blocks. bn>>10: 0->q(o0,b0), 1->k(o1,b1),
//         2->v(b2) transposed [b,e,s] into o2.
// MODE 2: exp(s*scale) bf16 into o0 + atomic row sums into lsum. 256 blocks.
// MODE 3: fp32 out = acc / lsum[row] into o3. 256 blocks (BN=128).
// ---------------------------------------------------------------------------
template<int MODE>
__global__ __launch_bounds__(512, 2) void gemm8(
    const u16* __restrict__ A, const u16* __restrict__ Bt,
    const float* __restrict__ b0, const float* __restrict__ b1, const float* __restrict__ b2,
    u16* __restrict__ o0, u16* __restrict__ o1, u16* __restrict__ o2,
    float* __restrict__ o3, float* __restrict__ lsum,
    int M, int N, int K, long sA, long sB, long sC, float scale)
{
    extern __shared__ __align__(16) u16 smem[];
    constexpr int NJ = (MODE == 3) ? 2 : 4;      // acc N columns / B frags

    const int t = threadIdx.x;
    const int lane = t & 63;
    const int wave = t >> 6;
    const int wm = wave >> 2;   // 0..1
    const int wn = wave & 3;    // 0..3

    const int id = blockIdx.x;
    const int xcd = id & 7;
    const int s = id >> 3;
    int bm, bn;
    long bz;
    if (MODE == 0) {            // 384 blocks: 32 bm x 12 bn
        bm = (xcd * 4 + (s & 3)) * 256;
        bn = (s >> 2) * 256;
        bz = 0;
    } else if (MODE == 2) {     // 256 blocks: 8 bm x 8 bn x 4 z
        bz = xcd >> 1;
        bm = ((xcd & 1) * 4 + (s & 3)) * 256;
        bn = (s >> 2) * 256;
    } else {                    // 256 blocks: 8 bm x 8 bn(128) x 4 z
        bz = xcd >> 1;
        bm = ((xcd & 1) * 4 + (s & 3)) * 256;
        bn = (s >> 2) * 128;
    }

    const u16* Ab = A + bz * sA;
    const u16* Bb = Bt + bz * sB;

    f32x4 acc[8][NJ];
#pragma unroll
    for (int i = 0; i < 8; ++i)
#pragma unroll
        for (int j = 0; j < NJ; ++j)
            acc[i][j] = (f32x4){0.f, 0.f, 0.f, 0.f};

    // ---- staging addressing (per-thread, inverse-swizzled global source) ----
    const int trow = t >> 2;                             // 0..127
    const int gcol = ((t & 3) * 8) ^ ((trow & 8) << 1);  // swz within 32 cols
    const u16* aRow = Ab + (long)(bm + trow) * K + gcol;
    const u16* bRow = Bb + (long)(bn + trow) * K + gcol;

    // one global_load_lds instr: chunk (isB, h, kb) of K-tile kt into buf
    auto stage1 = [&](int buf, int kt, int isB, int h, int kb) {
        const u16* g = (isB ? bRow : aRow) + (long)(h * 128) * K + kt * 64 + kb * 32;
        u16* d = smem + buf * 32768 + isB * 16384 + h * 8192 + kb * 4096 + t * 8;
        __builtin_amdgcn_global_load_lds(
            (const __attribute__((address_space(1))) void*)g,
            (__attribute__((address_space(3))) void*)d, 16, 0, 0);
    };

    // ---- fragment read addressing (swizzled ds_read) ----
    const int fm = lane & 15;
    const int fcol = ((lane >> 4) * 8) ^ ((fm & 8) << 1);
    const int aB = wm * 8192 + fm * 32 + fcol;           // + KH*4096 + MH*2048 + mi*512
    const int bB = (MODE == 3)
        ? 16384 + wn * 1024 + fm * 32 + fcol             // + KH*4096 + ni*512
        : 16384 + (wn >> 1) * 8192 + (wn & 1) * 2048 + fm * 32 + fcol;

    bf16x8 aCur[4], aNxt[4], bCur[NJ], bNxt[NJ];

#define RD_A(DST, BUF, MH, KH) do { \
    _Pragma("unroll") for (int mi = 0; mi < 4; ++mi) \
        DST[mi] = *(const bf16x8*)&smem[(BUF)*32768 + aB + (KH)*4096 + (MH)*2048 + mi*512]; \
} while (0)

#define RD_B(DST, BUF, KH) do { \
    _Pragma("unroll") for (int ni = 0; ni < NJ; ++ni) \
        DST[ni] = *(const bf16x8*)&smem[(BUF)*32768 + bB + (KH)*4096 + ni*512]; \
} while (0)

#define PH(MH, FA, FB) do { \
    __builtin_amdgcn_s_setprio(1); \
    _Pragma("unroll") for (int mi = 0; mi < 4; ++mi) \
    _Pragma("unroll") for (int ni = 0; ni < NJ; ++ni) \
        acc[(MH)*4+mi][ni] = __builtin_amdgcn_mfma_f32_16x16x32_bf16( \
            FA[mi], FB[ni], acc[(MH)*4+mi][ni], 0, 0, 0); \
    __builtin_amdgcn_s_setprio(0); \
} while (0)

    const int NT = K >> 6;
    const int NI = NT >> 1;

    // ---- prologue: buf0 <- tile0 (full), buf1 <- tile1 {Bk0, Ak0} ----
    stage1(0, 0, 1, 0, 0); if (MODE != 3) stage1(0, 0, 1, 1, 0);  // B0k0
    stage1(0, 0, 0, 0, 0); stage1(0, 0, 0, 1, 0);                 // A0k0
    stage1(0, 0, 1, 0, 1); if (MODE != 3) stage1(0, 0, 1, 1, 1);  // B0k1
    stage1(0, 0, 0, 0, 1); stage1(0, 0, 0, 1, 1);                 // A0k1
    stage1(1, 1, 1, 0, 0); if (MODE != 3) stage1(1, 1, 1, 1, 0);  // B1k0
    stage1(1, 1, 0, 0, 0); stage1(1, 1, 0, 1, 0);                 // A1k0
    if (MODE == 3) { VMW(6); } else { VMW(8); }   // retire B0k0+A0k0
    BAR();
    RD_A(aCur, 0, 0, 0); RD_B(bCur, 0, 0);        // P1 frags (tile 0, kh0)

    for (int i = 0; i < NI; ++i) {
        const int t1 = 2 * i + 1;
        int t2 = 2 * i + 2; if (t2 >= NT) t2 -= NT;
        int t3 = 2 * i + 3; if (t3 >= NT) t3 -= NT;

        // P1: mh0*kh0(buf0)
        PH(0, aCur, bCur);
        RD_A(aNxt, 0, 1, 0);
        stage1(1, t1, 1, 0, 1); if (MODE != 3) stage1(1, t1, 1, 1, 1); // B1k1
        if (MODE == 3) { VMW(4); } else { VMW(6); }
        BAR();
        // P2: mh1*kh0(buf0)
        PH(1, aNxt, bCur);
        RD_A(aCur, 0, 0, 1); RD_B(bNxt, 0, 1);
        stage1(1, t1, 0, 0, 1); stage1(1, t1, 0, 1, 1);               // A1k1
        BAR();
        // P3: mh0*kh1(buf0)
        PH(0, aCur, bNxt);
        RD_A(aNxt, 0, 1, 1);
        stage1(0, t2, 1, 0, 0); if (MODE != 3) stage1(0, t2, 1, 1, 0); // B0k0
        if (MODE == 3) { VMW(4); } else { VMW(6); }
        BAR();
        // P4: mh1*kh1(buf0)
        PH(1, aNxt, bNxt);
        RD_A(aCur, 1, 0, 0); RD_B(bCur, 1, 0);
        stage1(0, t2, 0, 0, 0); stage1(0, t2, 0, 1, 0);               // A0k0
        BAR();
        // P5: mh0*kh0(buf1)
        PH(0, aCur, bCur);
        RD_A(aNxt, 1, 1, 0);
        stage1(0, t2, 1, 0, 1); if (MODE != 3) stage1(0, t2, 1, 1, 1); // B0k1
        if (MODE == 3) { VMW(4); } else { VMW(6); }
        BAR();
        // P6: mh1*kh0(buf1)
        PH(1, aNxt, bCur);
        RD_A(aCur, 1, 0, 1); RD_B(bNxt, 1, 1);
        stage1(0, t2, 0, 0, 1); stage1(0, t2, 0, 1, 1);               // A0k1
        BAR();
        // P7: mh0*kh1(buf1)
        PH(0, aCur, bNxt);
        RD_A(aNxt, 1, 1, 1);
        stage1(1, t3, 1, 0, 0); if (MODE != 3) stage1(1, t3, 1, 1, 0); // B1k0
        if (MODE == 3) { VMW(4); } else { VMW(6); }
        BAR();
        // P8: mh1*kh1(buf1)
        PH(1, aNxt, bNxt);
        RD_A(aCur, 0, 0, 0); RD_B(bCur, 0, 0);    // next tile (t2) kh0
        stage1(1, t3, 0, 0, 0); stage1(1, t3, 0, 1, 0);               // A1k0
        BAR();
    }

    // ---- drain stale in-flight stagers before LDS reuse ----
    VMW(0);
    BAR();

    // C/D layout: col = lane&15, row = (lane>>4)*4 + reg
    const int cm = (lane >> 4) * 4;
    const int cn = lane & 15;
    u16* Ew = smem + wave * 8192;      // 16 KiB per-wave window
    const int gmb = bm + wm * 128;

    if constexpr (MODE == 3) {
        // ---- fp32 out (PV), /lsum[row]: 4 passes of 32 rows x 32 cols ----
        float* Fw = (float*)Ew;
        const int cnb3 = bn + wn * 32;
#pragma unroll
        for (int p = 0; p < 4; ++p) {
            if (p) lds_fence();
#pragma unroll
            for (int m2 = 0; m2 < 2; ++m2) {
                const int mi = p * 2 + m2;
#pragma unroll
                for (int ni = 0; ni < 2; ++ni)
#pragma unroll
                    for (int r = 0; r < 4; ++r)
                        Fw[(m2 * 16 + cm + r) * 36 + ni * 16 + cn] = acc[mi][ni][r];
            }
#pragma unroll
            for (int it = 0; it < 4; ++it) {
                const int row = it * 8 + (lane >> 3);
                const int c4 = (lane & 7) * 4;
                f32x4 w = *(const f32x4*)&Fw[row * 36 + c4];
                const int gm = gmb + p * 32 + row;
                const float inv = __builtin_amdgcn_rcpf(lsum[bz * 2048 + gm]);
                w[0] *= inv; w[1] *= inv; w[2] *= inv; w[3] *= inv;
                *(f32x4*)&o3[bz * sC + (long)gm * N + cnb3 + c4] = w;
            }
        }
    } else if (MODE == 0 && (bn >> 10) == 2) {
        // ---- v projection: transposed [b,e,s]; 2 s-passes of 64 ----
        const int ebase = (bn & 1023) + wn * 64;
        float bb[4];
#pragma unroll
        for (int ni = 0; ni < 4; ++ni) bb[ni] = b2[ebase + ni * 16 + cn];
        const long bgi = gmb >> 11;
        const int sbase = gmb & 2047;
#pragma unroll
        for (int p = 0; p < 2; ++p) {
            if (p) lds_fence();
#pragma unroll
            for (int m4 = 0; m4 < 4; ++m4) {
                const int mi = p * 4 + m4;
#pragma unroll
                for (int ni = 0; ni < 4; ++ni) {
                    ushort4 pk;
                    pk.x = f2bf(acc[mi][ni][0] + bb[ni]);
                    pk.y = f2bf(acc[mi][ni][1] + bb[ni]);
                    pk.z = f2bf(acc[mi][ni][2] + bb[ni]);
                    pk.w = f2bf(acc[mi][ni][3] + bb[ni]);
                    *(ushort4*)&Ew[(ni * 16 + cn) * 72 + m4 * 16 + cm] = pk; // [e][s]
                }
            }
#pragma unroll
            for (int it = 0; it < 8; ++it) {
                const int e = it * 8 + (lane >> 3);
                const int s8 = (lane & 7) * 8;
                const uint4 w = *(const uint4*)&Ew[e * 72 + s8];
                *(uint4*)&o2[(((bgi << 10) + ebase + e) << 11) + sbase + p * 64 + s8] = w;
            }
        }
    } else if (MODE == 0) {
        // ---- q/k projection, row-major bf16; 2 row-passes of 64 ----
        const int sec = bn >> 10;
        u16* C = sec ? o1 : o0;
        const float* bias = sec ? b1 : b0;
        const int ncol0 = (bn & 1023) + wn * 64;
        float bb[4];
#pragma unroll
        for (int ni = 0; ni < 4; ++ni) bb[ni] = bias[ncol0 + ni * 16 + cn];
#pragma unroll
        for (int p = 0; p < 2; ++p) {
            if (p) lds_fence();
#pragma unroll
            for (int m4 = 0; m4 < 4; ++m4) {
                const int mi = p * 4 + m4;
#pragma unroll
                for (int ni = 0; ni < 4; ++ni)
#pragma unroll
                    for (int r = 0; r < 4; ++r)
                        Ew[(m4 * 16 + cm + r) * 72 + ni * 16 + cn] = f2bf(acc[mi][ni][r] + bb[ni]);
            }
#pragma unroll
            for (int it = 0; it < 8; ++it) {
                const int row = it * 8 + (lane >> 3);
                const int c8 = (lane & 7) * 8;
                const uint4 w = *(const uint4*)&Ew[row * 72 + c8];
                *(uint4*)&C[(long)(gmb + p * 64 + row) * 1024 + ncol0 + c8] = w;
            }
        }
    } else {
        // ---- MODE 2: exp(s*scale), row-sum atomics, bf16 retile ----
        const int cnb = bn + wn * 64;
#pragma unroll
        for (int mi = 0; mi < 8; ++mi)
#pragma unroll
            for (int ni = 0; ni < 4; ++ni)
#pragma unroll
                for (int r = 0; r < 4; ++r)
                    acc[mi][ni][r] = __expf(acc[mi][ni][r] * scale);
#pragma unroll
        for (int mi = 0; mi < 8; ++mi) {
#pragma unroll
            for (int r = 0; r < 4; ++r) {
                float sm = acc[mi][0][r] + acc[mi][1][r] + acc[mi][2][r] + acc[mi][3][r];
                sm += __shfl_xor(sm, 1);
                sm += __shfl_xor(sm, 2);
                sm += __shfl_xor(sm, 4);
                sm += __shfl_xor(sm, 8);
                if (cn == 0)
                    atomicAdd(&lsum[bz * 2048 + gmb + mi * 16 + cm + r], sm);
            }
        }
#pragma unroll
        for (int p = 0; p < 2; ++p) {
            if (p) lds_fence();
#pragma unroll
            for (int m4 = 0; m4 < 4; ++m4) {
                const int mi = p * 4 + m4;
#pragma unroll
                for (int ni = 0; ni < 4; ++ni)
#pragma unroll
                    for (int r = 0; r < 4; ++r)
                        Ew[(m4 * 16 + cm + r) * 72 + ni * 16 + cn] = f2bf(acc[mi][ni][r]);
            }
#pragma unroll
            for (int it = 0; it < 8; ++it) {
                const int row = it * 8 + (lane >> 3);
                const int c8 = (lane & 7) * 8;
                const uint4 w = *(const uint4*)&Ew[row * 72 + c8];
                *(uint4*)&o0[bz * sC + (long)(gmb + p * 64 + row) * N + cnb + c8] = w;
            }
        }
    }
}

#undef RD_A
#undef RD_B
#undef PH

// fp32 -> bf16 converts + lsum zeroing.
__global__ __launch_bounds__(256) void cvt_all(
    const float* __restrict__ x, const float* __restrict__ wq,
    const float* __restrict__ wk, const float* __restrict__ wv,
    u16* __restrict__ xb, u16* __restrict__ wb, float* __restrict__ lsum)
{
    const int b = blockIdx.x;
    if (b >= 11264) {
        const long i = (long)(b - 11264) * 1024 + threadIdx.x * 4;
        *(f32x4*)(lsum + i) = (f32x4){0.f, 0.f, 0.f, 0.f};
        return;
    }
    const float* src; u16* dst; long base;
    if (b < 8192)       { src = x;  dst = xb;             base = (long)b * 1024; }
    else if (b < 9216)  { src = wq; dst = wb;             base = (long)(b - 8192) * 1024; }
    else if (b < 10240) { src = wk; dst = wb + (1 << 20); base = (long)(b - 9216) * 1024; }
    else                { src = wv; dst = wb + (2 << 20); base = (long)(b - 10240) * 1024; }
    const long i = base + threadIdx.x * 4;
    const f32x4 f = *(const f32x4*)(src + i);
    ushort4 o;
    o.x = f2bf(f[0]); o.y = f2bf(f[1]); o.z = f2bf(f[2]); o.w = f2bf(f[3]);
    *(ushort4*)(dst + i) = o;
}

extern "C" void kernel_launch(void* const* d_in, const int* in_sizes, int n_in,
                              void* d_out, int out_size, void* d_ws, size_t ws_size,
                              hipStream_t stream) {
    const float* x  = (const float*)d_in[0];
    const float* Wq = (const float*)d_in[1];
    const float* bq = (const float*)d_in[2];
    const float* Wk = (const float*)d_in[3];
    const float* bk = (const float*)d_in[4];
    const float* Wv = (const float*)d_in[5];
    const float* bv = (const float*)d_in[6];
    float* out = (float*)d_out;

    const int B = 4, S = 2048, D = 1024, E = 1024;
    const int M = B * S; // 8192
    const size_t LDS = 131072;

    u16* xb  = (u16*)d_ws;                       // [M,D]
    u16* wb  = xb  + (size_t)M * D;              // [3E,D]
    u16* qb  = wb  + (size_t)3 * E * D;          // [M,E]
    u16* kb  = qb  + (size_t)M * E;              // [M,E]
    u16* vbT = kb  + (size_t)M * E;              // [B,E,S]
    u16* sb  = vbT + (size_t)M * E;              // [B,S,S] exp-scores
    float* lsum = (float*)(sb + (size_t)M * S);  // [M]

    static bool attr_done = false;
    if (!attr_done) {
        (void)hipFuncSetAttribute((const void*)gemm8<0>, hipFuncAttributeMaxDynamicSharedMemorySize, (int)LDS);
        (void)hipFuncSetAttribute((const void*)gemm8<2>, hipFuncAttributeMaxDynamicSharedMemorySize, (int)LDS);
        (void)hipFuncSetAttribute((const void*)gemm8<3>, hipFuncAttributeMaxDynamicSharedMemorySize, (int)LDS);
        attr_done = true;
    }

    cvt_all<<<11272, 256, 0, stream>>>(x, Wq, Wk, Wv, xb, wb, lsum);

    dim3 blk(512);
    gemm8<0><<<384, blk, LDS, stream>>>(
        xb, wb, bq, bk, bv, qb, kb, vbT, nullptr, nullptr, M, 3 * E, D, 0, 0, 0, 1.f);
    gemm8<2><<<256, blk, LDS, stream>>>(
        qb, kb, nullptr, nullptr, nullptr, sb, nullptr, nullptr, nullptr, lsum,
        S, S, E, (long)S * E, (long)S * E, (long)S * S, 0.03125f);
    gemm8<3><<<256, blk, LDS, stream>>>(
        sb, vbT, nullptr, nullptr, nullptr, nullptr, nullptr, nullptr, out, lsum,
        S, E, S, (long)S * S, (long)E * S, (long)S * E, 1.f);
}